// Round 7
// baseline (176.359 us; speedup 1.0000x reference)
//
#include <hip/hip_runtime.h>
#include <cstddef>

#define DSZ 4096

// v[i] = g_mu[i] + softplus(g_rho[i]) * epsilon[i]
__global__ void compute_v_kernel(const float* __restrict__ eps,
                                 const float* __restrict__ g_mu,
                                 const float* __restrict__ g_rho,
                                 float* __restrict__ v) {
    int i = blockIdx.x * blockDim.x + threadIdx.x;
    if (i < DSZ) {
        float rho = g_rho[i];
        float sp = fmaxf(rho, 0.0f) + log1pf(expf(-fabsf(rho)));
        v[i] = g_mu[i] + sp * eps[i];
    }
}

// Global LDS swizzle (involution, bijective): XOR dword-addr bits 2-5 with
// bits 6-9. Conflict-free for all three access patterns (see R2 analysis).
__device__ __forceinline__ int swz(int a) {
    return a ^ (((a >> 6) & 15) << 2);
}

typedef float fv4 __attribute__((ext_vector_type(4)));
__device__ __forceinline__ void nt_store4(float* dst, float a, float b,
                                          float c, float d) {
    fv4 t;
    t.x = a; t.y = b; t.z = c; t.w = d;
    __builtin_nontemporal_store(t, (fv4*)dst);
}

// 4-stage FWHT over 16 registers, compile-time indices only.
#define FWHT16(Y) do {                                                  \
    _Pragma("unroll")                                                   \
    for (int s_ = 1; s_ < 16; s_ <<= 1) {                               \
        _Pragma("unroll")                                               \
        for (int r_ = 0; r_ < 16; ++r_) {                               \
            if ((r_ & s_) == 0) {                                       \
                float a_ = Y[r_];                                       \
                float b_ = Y[r_ | s_];                                  \
                Y[r_]      = a_ + b_;                                   \
                Y[r_ | s_] = a_ - b_;                                   \
            }                                                           \
        }                                                               \
    }                                                                   \
} while (0)

// Element-bit layouts (16 floats/thread, 256 threads/row):
//   A: i = 4*T + (r&3) + 1024*(r>>2)     regs = bits {0,1,10,11}
//   B: i = (T&3) + 4*r + 64*(T>>2)       regs = bits {2,3,4,5}
//   C: i = (T&63) + 64*r + 1024*(T>>6)   regs = bits {6,7,8,9}
// Processes one row already loaded into y (layout A, pre-scaled by s2):
// y <- FWHT(y); [optional prefetch of next row's x]; 4 swizzled LDS
// exchanges; multiply by v mid-stream; scale by s1; nt-store.
template <bool PF>
__device__ __forceinline__ void process_row(float* y, float* lds, int T,
                                            const float* __restrict__ v,
                                            const float* __restrict__ s1,
                                            float* __restrict__ outrow,
                                            const float4* __restrict__ x1,
                                            float4* p) {
    FWHT16(y);                       // bits 0,1,10,11

    // ---- exchange A -> B ----
    #pragma unroll
    for (int j = 0; j < 4; ++j)
        *(float4*)&lds[swz(4 * T + 1024 * j)] =
            make_float4(y[4 * j], y[4 * j + 1], y[4 * j + 2], y[4 * j + 3]);
    if (PF) {                        // issue next row's loads under the
        #pragma unroll               // upcoming 4-exchange LDS chain (T14)
        for (int j = 0; j < 4; ++j)
            p[j] = x1[T + 256 * j];
    }
    __syncthreads();
    #pragma unroll
    for (int r = 0; r < 16; ++r)
        y[r] = lds[swz((T & 3) + 4 * r + 64 * (T >> 2))];

    FWHT16(y);                       // bits 2-5

    // ---- exchange B -> C (same-thread slot rewrite: no pre-barrier) ----
    #pragma unroll
    for (int r = 0; r < 16; ++r)
        lds[swz((T & 3) + 4 * r + 64 * (T >> 2))] = y[r];
    __syncthreads();
    #pragma unroll
    for (int r = 0; r < 16; ++r)
        y[r] = lds[swz((T & 63) + 64 * r + 1024 * (T >> 6))];

    FWHT16(y);                       // bits 6-9 (transform 1 done)

    const float* vb = v + (T & 63) + 1024 * (T >> 6);
    #pragma unroll
    for (int r = 0; r < 16; ++r)
        y[r] *= vb[64 * r];          // diagonal, L2-resident

    FWHT16(y);                       // bits 6-9 (transform 2 begins)

    // ---- exchange C -> B ----
    #pragma unroll
    for (int r = 0; r < 16; ++r)
        lds[swz((T & 63) + 64 * r + 1024 * (T >> 6))] = y[r];
    __syncthreads();
    #pragma unroll
    for (int r = 0; r < 16; ++r)
        y[r] = lds[swz((T & 3) + 4 * r + 64 * (T >> 2))];

    FWHT16(y);                       // bits 2-5

    // ---- exchange B -> A ----
    #pragma unroll
    for (int r = 0; r < 16; ++r)
        lds[swz((T & 3) + 4 * r + 64 * (T >> 2))] = y[r];
    __syncthreads();
    #pragma unroll
    for (int j = 0; j < 4; ++j) {
        float4 t4 = *(const float4*)&lds[swz(4 * T + 1024 * j)];
        y[4 * j + 0] = t4.x;
        y[4 * j + 1] = t4.y;
        y[4 * j + 2] = t4.z;
        y[4 * j + 3] = t4.w;
    }

    FWHT16(y);                       // bits 0,1,10,11 (done)

    // ---- scale by s1, non-temporal store (don't evict x from L2/L3) ----
    const float4* s14 = (const float4*)s1;
    #pragma unroll
    for (int j = 0; j < 4; ++j) {
        float4 sv = s14[T + 256 * j];
        nt_store4(outrow + 4 * (T + 256 * j),
                  y[4 * j + 0] * sv.x, y[4 * j + 1] * sv.y,
                  y[4 * j + 2] * sv.z, y[4 * j + 3] * sv.w);
    }
    // NOTE: next row's A-pattern LDS writes hit exactly the slots THIS
    // thread just read in the A-pattern read above -> no barrier needed
    // at the row boundary.
}

// Two rows per block; row 1's x prefetched during row 0's exchange chain.
__global__ __launch_bounds__(256, 6) void whvi_kernel(
        const float* __restrict__ x,
        const float* __restrict__ s1,
        const float* __restrict__ s2,
        const float* __restrict__ v,
        float* __restrict__ out) {
    __shared__ float lds[DSZ];
    const int T = threadIdx.x;
    const size_t row0 = 2 * (size_t)blockIdx.x;

    const float4* x0 = (const float4*)(x + row0 * DSZ);
    const float4* x1 = (const float4*)(x + (row0 + 1) * DSZ);

    // s2 cached in registers (reused by both rows)
    const float4* s24 = (const float4*)s2;
    float4 s2r[4];
    #pragma unroll
    for (int j = 0; j < 4; ++j)
        s2r[j] = s24[T + 256 * j];

    float y[16];
    float4 p[4];

    // ---- row 0: load x*s2 in layout A (lane-contiguous float4) ----
    #pragma unroll
    for (int j = 0; j < 4; ++j) {
        float4 xv = x0[T + 256 * j];
        y[4 * j + 0] = xv.x * s2r[j].x;
        y[4 * j + 1] = xv.y * s2r[j].y;
        y[4 * j + 2] = xv.z * s2r[j].z;
        y[4 * j + 3] = xv.w * s2r[j].w;
    }
    process_row<true>(y, lds, T, v, s1, out + row0 * DSZ, x1, p);

    // ---- row 1: prefetched x already in p ----
    #pragma unroll
    for (int j = 0; j < 4; ++j) {
        y[4 * j + 0] = p[j].x * s2r[j].x;
        y[4 * j + 1] = p[j].y * s2r[j].y;
        y[4 * j + 2] = p[j].z * s2r[j].z;
        y[4 * j + 3] = p[j].w * s2r[j].w;
    }
    process_row<false>(y, lds, T, v, s1, out + (row0 + 1) * DSZ, x1, p);
}

extern "C" void kernel_launch(void* const* d_in, const int* in_sizes, int n_in,
                              void* d_out, int out_size, void* d_ws, size_t ws_size,
                              hipStream_t stream) {
    // setup_inputs order: x, epsilon, s1, s2, g_mu, g_rho
    const float* x     = (const float*)d_in[0];
    const float* eps   = (const float*)d_in[1];
    const float* s1    = (const float*)d_in[2];
    const float* s2    = (const float*)d_in[3];
    const float* g_mu  = (const float*)d_in[4];
    const float* g_rho = (const float*)d_in[5];
    float* out = (float*)d_out;
    float* v   = (float*)d_ws;   // 16 KB scratch

    compute_v_kernel<<<DSZ / 256, 256, 0, stream>>>(eps, g_mu, g_rho, v);
    whvi_kernel<<<DSZ / 2, 256, 0, stream>>>(x, s1, s2, v, out);
}

// Round 13
// 125.669 us; speedup vs baseline: 1.4034x; 1.4034x over previous
//
#include <hip/hip_runtime.h>
#include <cstddef>

#define DSZ 4096

// v[i] = g_mu[i] + softplus(g_rho[i]) * epsilon[i]
__global__ void compute_v_kernel(const float* __restrict__ eps,
                                 const float* __restrict__ g_mu,
                                 const float* __restrict__ g_rho,
                                 float* __restrict__ v) {
    int i = blockIdx.x * blockDim.x + threadIdx.x;
    if (i < DSZ) {
        float rho = g_rho[i];
        float sp = fmaxf(rho, 0.0f) + log1pf(expf(-fabsf(rho)));
        v[i] = g_mu[i] + sp * eps[i];
    }
}

// Global LDS swizzle (involution, bijective): XOR dword-addr bits 2-5 with
// bits 6-9. Conflict-free for all three access patterns (see R2 analysis).
__device__ __forceinline__ int swz(int a) {
    return a ^ (((a >> 6) & 15) << 2);
}

typedef float fv4 __attribute__((ext_vector_type(4)));
__device__ __forceinline__ void nt_store4(float* dst, float a, float b,
                                          float c, float d) {
    fv4 t;
    t.x = a; t.y = b; t.z = c; t.w = d;
    __builtin_nontemporal_store(t, (fv4*)dst);
}

// 4-stage FWHT over 16 registers, compile-time indices only.
#define FWHT16(Y) do {                                                  \
    _Pragma("unroll")                                                   \
    for (int s_ = 1; s_ < 16; s_ <<= 1) {                               \
        _Pragma("unroll")                                               \
        for (int r_ = 0; r_ < 16; ++r_) {                               \
            if ((r_ & s_) == 0) {                                       \
                float a_ = Y[r_];                                       \
                float b_ = Y[r_ | s_];                                  \
                Y[r_]      = a_ + b_;                                   \
                Y[r_ | s_] = a_ - b_;                                   \
            }                                                           \
        }                                                               \
    }                                                                   \
} while (0)

// Element-bit layouts (16 floats/thread, 256 threads/row):
//   A: i = 4*T + (r&3) + 1024*(r>>2)     regs = bits {0,1,10,11}
//   B: i = (T&3) + 4*r + 64*(T>>2)       regs = bits {2,3,4,5}
//   C: i = (T&63) + 64*r + 1024*(T>>6)   regs = bits {6,7,8,9}
//
// ROW_MIDDLE: everything between the A-pattern LDS write and the final
// FWHT — 3 barriers of the 4-exchange chain + the v-diagonal. Expanded as a
// MACRO in kernel scope (not a function): y[] stays SROA-promotable, every
// index compile-time => registers, no scratch (R7 post-mortem: passing y by
// pointer demoted it to scratch, VGPR 40, +170 MB HBM leak, 83us).
#define ROW_MIDDLE() do {                                               \
    __syncthreads();                                                    \
    _Pragma("unroll")                                                   \
    for (int r = 0; r < 16; ++r)                                        \
        y[r] = lds[swz((T & 3) + 4 * r + 64 * (T >> 2))];               \
    FWHT16(y);                       /* bits 2-5 */                     \
    _Pragma("unroll")                /* B->C: same-slot rewrite */      \
    for (int r = 0; r < 16; ++r)                                        \
        lds[swz((T & 3) + 4 * r + 64 * (T >> 2))] = y[r];               \
    __syncthreads();                                                    \
    _Pragma("unroll")                                                   \
    for (int r = 0; r < 16; ++r)                                        \
        y[r] = lds[swz((T & 63) + 64 * r + 1024 * (T >> 6))];           \
    FWHT16(y);                       /* bits 6-9 (transform 1 done) */  \
    _Pragma("unroll")                                                   \
    for (int r = 0; r < 16; ++r)                                        \
        y[r] *= vb[64 * r];          /* diagonal v, L2-resident */      \
    FWHT16(y);                       /* bits 6-9 (transform 2) */       \
    _Pragma("unroll")                /* C->B: same-slot rewrite */      \
    for (int r = 0; r < 16; ++r)                                        \
        lds[swz((T & 63) + 64 * r + 1024 * (T >> 6))] = y[r];           \
    __syncthreads();                                                    \
    _Pragma("unroll")                                                   \
    for (int r = 0; r < 16; ++r)                                        \
        y[r] = lds[swz((T & 3) + 4 * r + 64 * (T >> 2))];               \
    FWHT16(y);                       /* bits 2-5 */                     \
    _Pragma("unroll")                /* B->A: same-slot rewrite */      \
    for (int r = 0; r < 16; ++r)                                        \
        lds[swz((T & 3) + 4 * r + 64 * (T >> 2))] = y[r];               \
    __syncthreads();                                                    \
    _Pragma("unroll")                                                   \
    for (int j = 0; j < 4; ++j) {                                       \
        float4 t4 = *(const float4*)&lds[swz(4 * T + 1024 * j)];        \
        y[4 * j + 0] = t4.x; y[4 * j + 1] = t4.y;                       \
        y[4 * j + 2] = t4.z; y[4 * j + 3] = t4.w;                       \
    }                                                                   \
    FWHT16(y);                       /* bits 0,1,10,11 (done) */        \
} while (0)

// Two rows per block; row 1's x prefetched into registers under row 0's
// LDS-exchange chain (T14 async-stage). launch_bounds (256,4): VGPR cap
// 128 => spill-proof; 16 waves/CU; LDS 16KB => 4 blocks/CU.
__global__ __launch_bounds__(256, 4) void whvi_kernel(
        const float* __restrict__ x,
        const float* __restrict__ s1,
        const float* __restrict__ s2,
        const float* __restrict__ v,
        float* __restrict__ out) {
    __shared__ float lds[DSZ];
    const int T = threadIdx.x;
    const size_t row0 = 2 * (size_t)blockIdx.x;

    const float4* x0  = (const float4*)(x + row0 * DSZ);
    const float4* x1  = x0 + DSZ / 4;
    const float4* s24 = (const float4*)s2;
    const float4* s14 = (const float4*)s1;
    const float*  vb  = v + (T & 63) + 1024 * (T >> 6);

    float y[16];
    float4 p[4];

    // ================= ROW 0 =================
    #pragma unroll
    for (int j = 0; j < 4; ++j) {
        float4 xv = x0[T + 256 * j];
        float4 sv = s24[T + 256 * j];
        y[4 * j + 0] = xv.x * sv.x;
        y[4 * j + 1] = xv.y * sv.y;
        y[4 * j + 2] = xv.z * sv.z;
        y[4 * j + 3] = xv.w * sv.w;
    }

    FWHT16(y);                       // bits 0,1,10,11

    #pragma unroll                   // A-pattern write (exchange A->B)
    for (int j = 0; j < 4; ++j)
        *(float4*)&lds[swz(4 * T + 1024 * j)] =
            make_float4(y[4 * j], y[4 * j + 1], y[4 * j + 2], y[4 * j + 3]);

    #pragma unroll                   // prefetch row 1 under the LDS chain
    for (int j = 0; j < 4; ++j)
        p[j] = x1[T + 256 * j];

    ROW_MIDDLE();

    {   // scale by s1, NT store (don't evict x from L2/L3)
        float* outrow = out + row0 * DSZ;
        #pragma unroll
        for (int j = 0; j < 4; ++j) {
            float4 sv = s14[T + 256 * j];
            nt_store4(outrow + 4 * (T + 256 * j),
                      y[4 * j + 0] * sv.x, y[4 * j + 1] * sv.y,
                      y[4 * j + 2] * sv.z, y[4 * j + 3] * sv.w);
        }
    }

    // ================= ROW 1 =================
    // Row-boundary needs no barrier: row 1's A-pattern writes hit exactly
    // the slots THIS thread just read in row 0's final A-pattern read.
    #pragma unroll
    for (int j = 0; j < 4; ++j) {
        float4 sv = s24[T + 256 * j];
        y[4 * j + 0] = p[j].x * sv.x;
        y[4 * j + 1] = p[j].y * sv.y;
        y[4 * j + 2] = p[j].z * sv.z;
        y[4 * j + 3] = p[j].w * sv.w;
    }

    FWHT16(y);                       // bits 0,1,10,11

    #pragma unroll                   // A-pattern write (exchange A->B)
    for (int j = 0; j < 4; ++j)
        *(float4*)&lds[swz(4 * T + 1024 * j)] =
            make_float4(y[4 * j], y[4 * j + 1], y[4 * j + 2], y[4 * j + 3]);

    ROW_MIDDLE();

    {   // scale by s1, NT store
        float* outrow = out + (row0 + 1) * DSZ;
        #pragma unroll
        for (int j = 0; j < 4; ++j) {
            float4 sv = s14[T + 256 * j];
            nt_store4(outrow + 4 * (T + 256 * j),
                      y[4 * j + 0] * sv.x, y[4 * j + 1] * sv.y,
                      y[4 * j + 2] * sv.z, y[4 * j + 3] * sv.w);
        }
    }
}

extern "C" void kernel_launch(void* const* d_in, const int* in_sizes, int n_in,
                              void* d_out, int out_size, void* d_ws, size_t ws_size,
                              hipStream_t stream) {
    // setup_inputs order: x, epsilon, s1, s2, g_mu, g_rho
    const float* x     = (const float*)d_in[0];
    const float* eps   = (const float*)d_in[1];
    const float* s1    = (const float*)d_in[2];
    const float* s2    = (const float*)d_in[3];
    const float* g_mu  = (const float*)d_in[4];
    const float* g_rho = (const float*)d_in[5];
    float* out = (float*)d_out;
    float* v   = (float*)d_ws;   // 16 KB scratch

    compute_v_kernel<<<DSZ / 256, 256, 0, stream>>>(eps, g_mu, g_rho, v);
    whvi_kernel<<<DSZ / 2, 256, 0, stream>>>(x, s1, s2, v, out);
}